// Round 4
// baseline (13451.999 us; speedup 1.0000x reference)
//
#include <hip/hip_runtime.h>
#include <hip/hip_fp16.h>

typedef _Float16 f16;
typedef _Float16 f16x8 __attribute__((ext_vector_type(8)));
typedef float    f32x4 __attribute__((ext_vector_type(4)));
typedef unsigned short ushort;

__device__ __forceinline__ float sigm(float x) { return 1.f / (1.f + __expf(-x)); }
__device__ __forceinline__ float reluf(float x) { return x > 0.f ? x : 0.f; }
__device__ __forceinline__ float h2f(ushort u) { return (float)__builtin_bit_cast(f16, u); }

#define LDACQ(p)    __hip_atomic_load((p), __ATOMIC_ACQUIRE, __HIP_MEMORY_SCOPE_AGENT)
#define STREL(p, v) __hip_atomic_store((p), (v), __ATOMIC_RELEASE, __HIP_MEMORY_SCOPE_AGENT)

// ---------------- pack B for MFMA b-frag layout (validated R1-R3)
// dst[((c*KF+kf)*64+L)*8+j] = B[kf*32 + (L>>4)*8 + j][c*16 + (L&15)]
template <int KF>
__global__ void pack_bsw(const float* __restrict__ B, f16* __restrict__ dst, int N) {
  int id = blockIdx.x * 256 + threadIdx.x;
  int total = KF * 32 * N;
  if (id >= total) return;
  int j  = id & 7;
  int L  = (id >> 3) & 63;
  int r  = id >> 9;
  int kf = r & (KF - 1);
  int c  = r / KF;
  int k  = kf * 32 + ((L >> 4) * 8) + j;
  int n  = c * 16 + (L & 15);
  dst[id] = (f16)B[k * N + n];
}

// ---------------- xW GEMM: gather(emb,tok)@B + bias -> scattered into recurrence
// x-layout. MODE 0 = paragraph (S=512, N=1024), MODE 1 = title (S=64, N=512).
// Para x addr: ((((g*512+t)*4+bb)*256 + wv*64+qc*16+l)*16 + rr*4+gamma)
// Title x addr: ((((g*64 +t)*2+bb)*256 + wv*64+qc*16+l)*16 + rr*4+gamma)
template <int K, int KF, int N, int NC, int MODE>
__global__ __launch_bounds__(256) void gemm_xw(const int* __restrict__ tok,
                                               const float* __restrict__ emb,
                                               const f16* __restrict__ Bsw,
                                               const float* __restrict__ bias,
                                               f16* __restrict__ X) {
  __shared__ int tokLds[64];
  __shared__ f16x8 bLds[8 * 64];
  const int tid = threadIdx.x;
  const int blk = blockIdx.x;
  if (tid < 64) tokLds[tid] = tok[blk * 64 + tid];
  __syncthreads();
  const int wave = tid >> 6, lane = tid & 63;
  const int quad = lane >> 4, l16 = lane & 15;
  const int m0 = wave * 16;

  f16x8 a[KF];
  {
    const int row = m0 + l16;
    const float* arow = emb + (long)tokLds[row] * K + quad * 8;
#pragma unroll
    for (int kf = 0; kf < KF; kf++) {
      float4 v0 = *(const float4*)(arow + kf * 32);
      float4 v1 = *(const float4*)(arow + kf * 32 + 4);
      f16x8 tv;
      tv[0] = (f16)v0.x; tv[1] = (f16)v0.y; tv[2] = (f16)v0.z; tv[3] = (f16)v0.w;
      tv[4] = (f16)v1.x; tv[5] = (f16)v1.y; tv[6] = (f16)v1.z; tv[7] = (f16)v1.w;
      a[kf] = tv;
    }
  }
  const f16x8* Bfrag = (const f16x8*)Bsw;
  for (int c = 0; c < NC; c++) {
    for (int i = tid; i < KF * 64; i += 256) bLds[i] = Bfrag[c * KF * 64 + i];
    __syncthreads();
    f32x4 acc = {0.f, 0.f, 0.f, 0.f};
#pragma unroll
    for (int kf = 0; kf < KF; kf++)
      acc = __builtin_amdgcn_mfma_f32_16x16x32_f16(a[kf], bLds[kf * 64 + lane], acc, 0, 0, 0);
    const int col = c * 16 + l16;
    const float bc = bias[col];
#pragma unroll
    for (int r = 0; r < 4; r++) {
      float v = acc[r] + bc;
      int row = blk * 64 + m0 + quad * 4 + r;
      size_t addr;
      if (MODE == 0) {
        int seqg = row >> 9, t = row & 511;
        int gg = seqg >> 4, si = seqg & 15, qc = si >> 2, rr = si & 3;
        int gm = col >> 8, u = col & 255, bb = u >> 6, wv = (u >> 4) & 3, l = u & 15;
        addr = (((size_t)((gg * 512 + t) * 4 + bb) * 256 + (wv * 64 + qc * 16 + l)) * 16 + rr * 4 + gm);
      } else {
        int seqg = row >> 6, t = row & 63;
        int gg = seqg >> 4, si = seqg & 15, qc = si >> 2, rr = si & 3;
        int gm = col >> 7, u = col & 127, bb = u >> 6, wv = (u >> 4) & 3, l = u & 15;
        addr = (((size_t)((gg * 64 + t) * 2 + bb) * 256 + (wv * 64 + qc * 16 + l)) * 16 + rr * 4 + gm);
      }
      X[addr] = (f16)v;
    }
    __syncthreads();
  }
}

// ---------------- init: zero counters + ring slot 7 (the t=-1 state)
__global__ void init_sync(int* __restrict__ cnt, f16* __restrict__ h0r,
                          f16* __restrict__ h1r, f16* __restrict__ h0tr) {
  int i = blockIdx.x * 256 + threadIdx.x;
  int n = gridDim.x * 256;
  for (int k = i; k < 96; k += n) cnt[k] = 0;
  for (int k = i; k < 8 * 4096; k += n) h0r[(k >> 12) * 32768 + 7 * 4096 + (k & 4095)] = (f16)0.f;
  for (int k = i; k < 8 * 2048; k += n) h1r[(k >> 11) * 16384 + 7 * 2048 + (k & 2047)] = (f16)0.f;
  for (int k = i; k < 8 * 2048; k += n) h0tr[(k >> 11) * 16384 + 7 * 2048 + (k & 2047)] = (f16)0.f;
}

// ---------------- persistent pipelined recurrence
// 96 blocks of 256 thr. role = blk>>3 (0-3 paraL0.bb, 4-7 paraL1.bb, 8 paraL2,
// 9-10 titleL0t.bb, 11 titleL1t), group g = blk&7 (same XCD under %8 mapping).
// Rings (8 slots): h0r [g][slot][16][256]; h1r [g][slot][bbregion4][16][32];
// h0tr [g][slot][16][128]. Counter cnt[blk] = steps completed.
struct RArgs {
  const f16 *xp2, *xt2;
  const f16 *U0f, *W1f, *U1f, *W2f, *U2f;
  const f16 *U0tf, *W1tf, *U1tf;
  const float *pl1_b, *pl2_b, *tl1_b;
  const float *pd0W, *pd0b, *pd1W, *pd1b, *pd2W, *pd2b;
  const float *td0W, *td0b, *td1W, *td1b, *td2W, *td2b;
  f16 *h0r, *h1r, *h0tr;
  int* cnt;
  float* feat;
};

__global__ __launch_bounds__(256, 1) void recur4(RArgs A) {
  __shared__ float zL[4160];
  __shared__ f16 hloc[16 * 80];
  const int tid = threadIdx.x;
  const int w = tid >> 6, lane = tid & 63;
  const int quad = lane >> 4, l16 = lane & 15;
  const int blk = blockIdx.x;
  const int role = blk >> 3, gq = blk & 7;
  int* mycnt = A.cnt + blk;

  if (role < 4) {
    // ========== paragraph L0: units 64*bb..+63, weights in registers ==========
    const int bb = role;
    const f16x8* U0v = (const f16x8*)A.U0f;
    const int ut = bb * 4 + w;
    f16x8 wreg[4][8];
#pragma unroll
    for (int gm = 0; gm < 4; gm++)
#pragma unroll
      for (int kf = 0; kf < 8; kf++)
        wreg[gm][kf] = U0v[((gm * 16 + ut) * 8 + kf) * 64 + lane];
    float c0[4] = {0.f, 0.f, 0.f, 0.f};
    const uint4* xP = (const uint4*)A.xp2;
    const size_t xb0 = ((size_t)(gq * 512 * 4 + bb) * 256 + tid) * 2;
    uint4 xc0 = xP[xb0], xc1 = xP[xb0 + 1];
    for (int t = 0; t < 512; t++) {
      const size_t xnb = xb0 + (size_t)(t + 1 < 512 ? t + 1 : t) * 2048;
      uint4 xn0 = xP[xnb], xn1 = xP[xnb + 1];
      if ((t & 3) == 0) {
        const int need = t - 4;
#pragma unroll
        for (int p = 0; p < 4; p++)
          while (LDACQ(A.cnt + (4 + p) * 8 + gq) < need) __builtin_amdgcn_s_sleep(1);
      }
#pragma unroll
      for (int p = 0; p < 4; p++)
        while (LDACQ(A.cnt + p * 8 + gq) < t) __builtin_amdgcn_s_sleep(1);
      const f16* hs = A.h0r + ((size_t)gq * 8 + ((t + 7) & 7)) * 4096;
      f16x8 af[8];
#pragma unroll
      for (int kf = 0; kf < 8; kf++)
        af[kf] = *(const f16x8*)(hs + l16 * 256 + kf * 32 + quad * 8);
      f32x4 acc[4];
#pragma unroll
      for (int gm = 0; gm < 4; gm++) {
        f32x4 z = {0.f, 0.f, 0.f, 0.f};
#pragma unroll
        for (int kf = 0; kf < 8; kf++)
          z = __builtin_amdgcn_mfma_f32_16x16x32_f16(af[kf], wreg[gm][kf], z, 0, 0, 0);
        acc[gm] = z;
      }
      ushort xs[16];
      *(uint4*)&xs[0] = xc0; *(uint4*)&xs[8] = xc1;
      f16* hw = A.h0r + ((size_t)gq * 8 + (t & 7)) * 4096 + 64 * bb + 16 * w + l16;
#pragma unroll
      for (int r = 0; r < 4; r++) {
        float gi = sigm(acc[0][r] + h2f(xs[r * 4 + 0]));
        float ff = sigm(acc[1][r] + h2f(xs[r * 4 + 1]));
        float gg = reluf(acc[2][r] + h2f(xs[r * 4 + 2]));
        float oo = sigm(acc[3][r] + h2f(xs[r * 4 + 3]));
        c0[r] = ff * c0[r] + gi * gg;
        hw[(quad * 4 + r) * 256] = (f16)(oo * reluf(c0[r]));
      }
      __threadfence();
      __syncthreads();
      if (tid == 0) STREL(mycnt, t + 1);
      xc0 = xn0; xc1 = xn1;
    }
  } else if (role < 8) {
    // ========== paragraph L1: units 32*bb..+31, wave w = gate w ==========
    const int bb = role - 4;
    const f16x8* W1v = (const f16x8*)A.W1f;
    const f16x8* U1v = (const f16x8*)A.U1f;
    const int ct0 = w * 8 + bb * 2;
    f16x8 wB[2][8], wU[2][4];
#pragma unroll
    for (int s = 0; s < 2; s++) {
#pragma unroll
      for (int kf = 0; kf < 8; kf++) wB[s][kf] = W1v[((ct0 + s) * 8 + kf) * 64 + lane];
#pragma unroll
      for (int kf = 0; kf < 4; kf++) wU[s][kf] = U1v[((ct0 + s) * 4 + kf) * 64 + lane];
    }
    float bias1[2];
#pragma unroll
    for (int s = 0; s < 2; s++) bias1[s] = A.pl1_b[w * 128 + bb * 32 + s * 16 + l16];
    float c1[2] = {0.f, 0.f};
    for (int t = 0; t < 512; t++) {
      if ((t & 3) == 0) {
        const int need = t - 4;
        while (LDACQ(A.cnt + 64 + gq) < need) __builtin_amdgcn_s_sleep(1);
      }
#pragma unroll
      for (int p = 0; p < 4; p++)
        while (LDACQ(A.cnt + p * 8 + gq) < t + 1) __builtin_amdgcn_s_sleep(1);
#pragma unroll
      for (int p = 0; p < 4; p++)
        while (LDACQ(A.cnt + (4 + p) * 8 + gq) < t) __builtin_amdgcn_s_sleep(1);
      const f16* hs0 = A.h0r + ((size_t)gq * 8 + (t & 7)) * 4096;
      const f16* hs1 = A.h1r + ((size_t)gq * 8 + ((t + 7) & 7)) * 2048;
      f16x8 af0[8], af1[4];
#pragma unroll
      for (int kf = 0; kf < 8; kf++)
        af0[kf] = *(const f16x8*)(hs0 + l16 * 256 + kf * 32 + quad * 8);
#pragma unroll
      for (int kf = 0; kf < 4; kf++)
        af1[kf] = *(const f16x8*)(hs1 + kf * 512 + l16 * 32 + quad * 8);
#pragma unroll
      for (int s = 0; s < 2; s++) {
        f32x4 z = {0.f, 0.f, 0.f, 0.f};
#pragma unroll
        for (int kf = 0; kf < 8; kf++)
          z = __builtin_amdgcn_mfma_f32_16x16x32_f16(af0[kf], wB[s][kf], z, 0, 0, 0);
#pragma unroll
        for (int kf = 0; kf < 4; kf++)
          z = __builtin_amdgcn_mfma_f32_16x16x32_f16(af1[kf], wU[s][kf], z, 0, 0, 0);
#pragma unroll
        for (int r = 0; r < 4; r++)
          zL[(quad * 4 + r) * 132 + w * 32 + s * 16 + l16] = z[r] + bias1[s];
      }
      __syncthreads();
#pragma unroll
      for (int e = 0; e < 2; e++) {
        const int idx = tid + 256 * e;
        const int sq = idx >> 5, un = idx & 31;
        float gi = sigm(zL[sq * 132 + un]);
        float ff = sigm(zL[sq * 132 + 32 + un]);
        float gg = reluf(zL[sq * 132 + 64 + un]);
        float oo = sigm(zL[sq * 132 + 96 + un]);
        c1[e] = ff * c1[e] + gi * gg;
        A.h1r[((size_t)gq * 8 + (t & 7)) * 2048 + bb * 512 + sq * 32 + un] =
            (f16)(oo * reluf(c1[e]));
      }
      __threadfence();
      __syncthreads();
      if (tid == 0) STREL(mycnt, t + 1);
    }
  } else if (role == 8) {
    // ========== paragraph L2 (64 units) + dense tail ==========
    const f16x8* W2v = (const f16x8*)A.W2f;
    const f16x8* U2v = (const f16x8*)A.U2f;
    f16x8 wB[4][4], wU[4][2];
    float bias2[4];
#pragma unroll
    for (int s = 0; s < 4; s++) {
      const int ct = w * 4 + s;
#pragma unroll
      for (int kf = 0; kf < 4; kf++) wB[s][kf] = W2v[(ct * 4 + kf) * 64 + lane];
#pragma unroll
      for (int kf = 0; kf < 2; kf++) wU[s][kf] = U2v[(ct * 2 + kf) * 64 + lane];
      bias2[s] = A.pl2_b[w * 64 + s * 16 + l16];
    }
    float c2[4] = {0.f, 0.f, 0.f, 0.f};
    for (int i = tid; i < 16 * 80; i += 256) hloc[i] = (f16)0.f;
    __syncthreads();
    for (int t = 0; t < 512; t++) {
#pragma unroll
      for (int p = 0; p < 4; p++)
        while (LDACQ(A.cnt + (4 + p) * 8 + gq) < t + 1) __builtin_amdgcn_s_sleep(1);
      const f16* hs1 = A.h1r + ((size_t)gq * 8 + (t & 7)) * 2048;
      f16x8 af0[4], af1[2];
#pragma unroll
      for (int kf = 0; kf < 4; kf++)
        af0[kf] = *(const f16x8*)(hs1 + kf * 512 + l16 * 32 + quad * 8);
#pragma unroll
      for (int kf = 0; kf < 2; kf++)
        af1[kf] = *(const f16x8*)(hloc + l16 * 80 + kf * 32 + quad * 8);
#pragma unroll
      for (int s = 0; s < 4; s++) {
        f32x4 z = {0.f, 0.f, 0.f, 0.f};
#pragma unroll
        for (int kf = 0; kf < 4; kf++)
          z = __builtin_amdgcn_mfma_f32_16x16x32_f16(af0[kf], wB[s][kf], z, 0, 0, 0);
#pragma unroll
        for (int kf = 0; kf < 2; kf++)
          z = __builtin_amdgcn_mfma_f32_16x16x32_f16(af1[kf], wU[s][kf], z, 0, 0, 0);
#pragma unroll
        for (int r = 0; r < 4; r++)
          zL[(quad * 4 + r) * 260 + w * 64 + s * 16 + l16] = z[r] + bias2[s];
      }
      __syncthreads();
#pragma unroll
      for (int e = 0; e < 4; e++) {
        const int idx = tid + 256 * e;
        const int sq = idx >> 6, un = idx & 63;
        float gi = sigm(zL[sq * 260 + un]);
        float ff = sigm(zL[sq * 260 + 64 + un]);
        float gg = reluf(zL[sq * 260 + 128 + un]);
        float oo = sigm(zL[sq * 260 + 192 + un]);
        c2[e] = ff * c2[e] + gi * gg;
        hloc[sq * 80 + un] = (f16)(oo * reluf(c2[e]));
      }
      __syncthreads();
      if (tid == 0) STREL(mycnt, t + 1);
    }
    // dense tail -> feat cols 32..63
#pragma unroll 1
    for (int e = 0; e < 8; e++) {
      const int idx = tid + 256 * e;
      const int sq = idx >> 7, j = idx & 127;
      float a = A.pd0b[j];
      for (int k = 0; k < 64; k++) a += (float)hloc[sq * 80 + k] * A.pd0W[k * 128 + j];
      zL[sq * 132 + j] = reluf(a);
    }
    __syncthreads();
#pragma unroll 1
    for (int e = 0; e < 4; e++) {
      const int idx = tid + 256 * e;
      const int sq = idx >> 6, j = idx & 63;
      float a = A.pd1b[j];
      for (int k = 0; k < 128; k++) a += zL[sq * 132 + k] * A.pd1W[k * 64 + j];
      zL[2112 + sq * 68 + j] = reluf(a);
    }
    __syncthreads();
#pragma unroll 1
    for (int e = 0; e < 2; e++) {
      const int idx = tid + 256 * e;
      const int sq = idx >> 5, j = idx & 31;
      float a = A.pd2b[j];
      for (int k = 0; k < 64; k++) a += zL[2112 + sq * 68 + k] * A.pd2W[k * 32 + j];
      A.feat[(gq * 16 + sq) * 64 + 32 + j] = a;
    }
  } else if (role < 11) {
    // ========== title L0t: units 64*bb..+63 of 128 ==========
    const int bb = role - 9;
    const f16x8* U0tv = (const f16x8*)A.U0tf;
    const int ut = bb * 4 + w;
    f16x8 wreg[4][4];
#pragma unroll
    for (int gm = 0; gm < 4; gm++)
#pragma unroll
      for (int kf = 0; kf < 4; kf++)
        wreg[gm][kf] = U0tv[((gm * 8 + ut) * 4 + kf) * 64 + lane];
    float c0[4] = {0.f, 0.f, 0.f, 0.f};
    const uint4* xP = (const uint4*)A.xt2;
    const size_t xb0 = ((size_t)(gq * 64 * 2 + bb) * 256 + tid) * 2;
    uint4 xc0 = xP[xb0], xc1 = xP[xb0 + 1];
    for (int t = 0; t < 64; t++) {
      const size_t xnb = xb0 + (size_t)(t + 1 < 64 ? t + 1 : t) * 1024;
      uint4 xn0 = xP[xnb], xn1 = xP[xnb + 1];
      if ((t & 3) == 0) {
        const int need = t - 4;
        while (LDACQ(A.cnt + 88 + gq) < need) __builtin_amdgcn_s_sleep(1);
      }
#pragma unroll
      for (int p = 0; p < 2; p++)
        while (LDACQ(A.cnt + (9 + p) * 8 + gq) < t) __builtin_amdgcn_s_sleep(1);
      const f16* hs = A.h0tr + ((size_t)gq * 8 + ((t + 7) & 7)) * 2048;
      f16x8 af[4];
#pragma unroll
      for (int kf = 0; kf < 4; kf++)
        af[kf] = *(const f16x8*)(hs + l16 * 128 + kf * 32 + quad * 8);
      f32x4 acc[4];
#pragma unroll
      for (int gm = 0; gm < 4; gm++) {
        f32x4 z = {0.f, 0.f, 0.f, 0.f};
#pragma unroll
        for (int kf = 0; kf < 4; kf++)
          z = __builtin_amdgcn_mfma_f32_16x16x32_f16(af[kf], wreg[gm][kf], z, 0, 0, 0);
        acc[gm] = z;
      }
      ushort xs[16];
      *(uint4*)&xs[0] = xc0; *(uint4*)&xs[8] = xc1;
      f16* hw = A.h0tr + ((size_t)gq * 8 + (t & 7)) * 2048 + 64 * bb + 16 * w + l16;
#pragma unroll
      for (int r = 0; r < 4; r++) {
        float gi = sigm(acc[0][r] + h2f(xs[r * 4 + 0]));
        float ff = sigm(acc[1][r] + h2f(xs[r * 4 + 1]));
        float gg = reluf(acc[2][r] + h2f(xs[r * 4 + 2]));
        float oo = sigm(acc[3][r] + h2f(xs[r * 4 + 3]));
        c0[r] = ff * c0[r] + gi * gg;
        hw[(quad * 4 + r) * 128] = (f16)(oo * reluf(c0[r]));
      }
      __threadfence();
      __syncthreads();
      if (tid == 0) STREL(mycnt, t + 1);
      xc0 = xn0; xc1 = xn1;
    }
  } else {
    // ========== title L1t (64 units) + dense tail ==========
    const f16x8* W1tv = (const f16x8*)A.W1tf;
    const f16x8* U1tv = (const f16x8*)A.U1tf;
    f16x8 wB[4][4], wU[4][2];
    float bias2[4];
#pragma unroll
    for (int s = 0; s < 4; s++) {
      const int ct = w * 4 + s;
#pragma unroll
      for (int kf = 0; kf < 4; kf++) wB[s][kf] = W1tv[(ct * 4 + kf) * 64 + lane];
#pragma unroll
      for (int kf = 0; kf < 2; kf++) wU[s][kf] = U1tv[(ct * 2 + kf) * 64 + lane];
      bias2[s] = A.tl1_b[w * 64 + s * 16 + l16];
    }
    float c2[4] = {0.f, 0.f, 0.f, 0.f};
    for (int i = tid; i < 16 * 80; i += 256) hloc[i] = (f16)0.f;
    __syncthreads();
    for (int t = 0; t < 64; t++) {
#pragma unroll
      for (int p = 0; p < 2; p++)
        while (LDACQ(A.cnt + (9 + p) * 8 + gq) < t + 1) __builtin_amdgcn_s_sleep(1);
      const f16* hs0 = A.h0tr + ((size_t)gq * 8 + (t & 7)) * 2048;
      f16x8 af0[4], af1[2];
#pragma unroll
      for (int kf = 0; kf < 4; kf++)
        af0[kf] = *(const f16x8*)(hs0 + l16 * 128 + kf * 32 + quad * 8);
#pragma unroll
      for (int kf = 0; kf < 2; kf++)
        af1[kf] = *(const f16x8*)(hloc + l16 * 80 + kf * 32 + quad * 8);
#pragma unroll
      for (int s = 0; s < 4; s++) {
        f32x4 z = {0.f, 0.f, 0.f, 0.f};
#pragma unroll
        for (int kf = 0; kf < 4; kf++)
          z = __builtin_amdgcn_mfma_f32_16x16x32_f16(af0[kf], wB[s][kf], z, 0, 0, 0);
#pragma unroll
        for (int kf = 0; kf < 2; kf++)
          z = __builtin_amdgcn_mfma_f32_16x16x32_f16(af1[kf], wU[s][kf], z, 0, 0, 0);
#pragma unroll
        for (int r = 0; r < 4; r++)
          zL[(quad * 4 + r) * 260 + w * 64 + s * 16 + l16] = z[r] + bias2[s];
      }
      __syncthreads();
#pragma unroll
      for (int e = 0; e < 4; e++) {
        const int idx = tid + 256 * e;
        const int sq = idx >> 6, un = idx & 63;
        float gi = sigm(zL[sq * 260 + un]);
        float ff = sigm(zL[sq * 260 + 64 + un]);
        float gg = reluf(zL[sq * 260 + 128 + un]);
        float oo = sigm(zL[sq * 260 + 192 + un]);
        c2[e] = ff * c2[e] + gi * gg;
        hloc[sq * 80 + un] = (f16)(oo * reluf(c2[e]));
      }
      __syncthreads();
      if (tid == 0) STREL(mycnt, t + 1);
    }
    // dense tail -> feat cols 0..31
#pragma unroll 1
    for (int e = 0; e < 8; e++) {
      const int idx = tid + 256 * e;
      const int sq = idx >> 7, j = idx & 127;
      float a = A.td0b[j];
      for (int k = 0; k < 64; k++) a += (float)hloc[sq * 80 + k] * A.td0W[k * 128 + j];
      zL[sq * 132 + j] = reluf(a);
    }
    __syncthreads();
#pragma unroll 1
    for (int e = 0; e < 4; e++) {
      const int idx = tid + 256 * e;
      const int sq = idx >> 6, j = idx & 63;
      float a = A.td1b[j];
      for (int k = 0; k < 128; k++) a += zL[sq * 132 + k] * A.td1W[k * 64 + j];
      zL[2112 + sq * 68 + j] = reluf(a);
    }
    __syncthreads();
#pragma unroll 1
    for (int e = 0; e < 2; e++) {
      const int idx = tid + 256 * e;
      const int sq = idx >> 5, j = idx & 31;
      float a = A.td2b[j];
      for (int k = 0; k < 64; k++) a += zL[2112 + sq * 68 + k] * A.td2W[k * 32 + j];
      A.feat[(gq * 16 + sq) * 64 + j] = a;
    }
  }
}

// ---------------- head: mean over 16, 4 dense layers, sigmoid
__global__ __launch_bounds__(256) void head_kernel(const float* __restrict__ feat,
    const float* __restrict__ L0W, const float* __restrict__ L0b,
    const float* __restrict__ L1W, const float* __restrict__ L1b,
    const float* __restrict__ L2W, const float* __restrict__ L2b,
    const float* __restrict__ L3W, const float* __restrict__ L3b,
    float* __restrict__ out) {
  __shared__ float xb[512];
  __shared__ float y0[2048];
  __shared__ float y1[1024];
  __shared__ float y2[512];
  const int tid = threadIdx.x;
  for (int idx = tid; idx < 512; idx += 256) {
    int b = idx >> 6, d = idx & 63;
    float s = 0.f;
    for (int n = 0; n < 16; n++) s += feat[(b * 16 + n) * 64 + d];
    xb[idx] = s * (1.f / 16.f);
  }
  __syncthreads();
  for (int idx = tid; idx < 2048; idx += 256) {
    int b = idx >> 8, j = idx & 255;
    float a = L0b[j];
    for (int k = 0; k < 64; k++) a += xb[b * 64 + k] * L0W[k * 256 + j];
    y0[idx] = reluf(a);
  }
  __syncthreads();
  for (int idx = tid; idx < 1024; idx += 256) {
    int b = idx >> 7, j = idx & 127;
    float a = L1b[j];
    for (int k = 0; k < 256; k++) a += y0[b * 256 + k] * L1W[k * 128 + j];
    y1[idx] = reluf(a);
  }
  __syncthreads();
  for (int idx = tid; idx < 512; idx += 256) {
    int b = idx >> 6, j = idx & 63;
    float a = L2b[j];
    for (int k = 0; k < 128; k++) a += y1[b * 128 + k] * L2W[k * 64 + j];
    y2[idx] = reluf(a);
  }
  __syncthreads();
  {
    int b = tid >> 5, j = tid & 31;
    float a = L3b[j];
    for (int k = 0; k < 64; k++) a += y2[b * 64 + k] * L3W[k * 32 + j];
    out[b * 32 + j] = 1.f / (1.f + __expf(-a));
  }
}

extern "C" void kernel_launch(void* const* d_in, const int* in_sizes, int n_in,
                              void* d_out, int out_size, void* d_ws, size_t ws_size,
                              hipStream_t stream) {
  const int*   t_tok = (const int*)d_in[0];
  const int*   p_tok = (const int*)d_in[1];
  const float* emb_t = (const float*)d_in[2];
  const float* emb_p = (const float*)d_in[3];
  const float* tl0_W = (const float*)d_in[4];
  const float* tl0_U = (const float*)d_in[5];
  const float* tl0_b = (const float*)d_in[6];
  const float* tl1_W = (const float*)d_in[7];
  const float* tl1_U = (const float*)d_in[8];
  const float* tl1_b = (const float*)d_in[9];
  const float* td0_W = (const float*)d_in[10];
  const float* td0_b = (const float*)d_in[11];
  const float* td1_W = (const float*)d_in[12];
  const float* td1_b = (const float*)d_in[13];
  const float* td2_W = (const float*)d_in[14];
  const float* td2_b = (const float*)d_in[15];
  const float* pl0_W = (const float*)d_in[16];
  const float* pl0_U = (const float*)d_in[17];
  const float* pl0_b = (const float*)d_in[18];
  const float* pl1_W = (const float*)d_in[19];
  const float* pl1_U = (const float*)d_in[20];
  const float* pl1_b = (const float*)d_in[21];
  const float* pl2_W = (const float*)d_in[22];
  const float* pl2_U = (const float*)d_in[23];
  const float* pl2_b = (const float*)d_in[24];
  const float* pd0_W = (const float*)d_in[25];
  const float* pd0_b = (const float*)d_in[26];
  const float* pd1_W = (const float*)d_in[27];
  const float* pd1_b = (const float*)d_in[28];
  const float* pd2_W = (const float*)d_in[29];
  const float* pd2_b = (const float*)d_in[30];
  const float* L0_W  = (const float*)d_in[31];
  const float* L0_b  = (const float*)d_in[32];
  const float* L1_W  = (const float*)d_in[33];
  const float* L1_b  = (const float*)d_in[34];
  const float* L2_W  = (const float*)d_in[35];
  const float* L2_b  = (const float*)d_in[36];
  const float* L3_W  = (const float*)d_in[37];
  const float* L3_b  = (const float*)d_in[38];

  char* ws = (char*)d_ws;
  size_t off = 0;
  auto alloc = [&](size_t bytes) {
    void* ptr = ws + off;
    off += (bytes + 255) & ~(size_t)255;
    return ptr;
  };
  f16* xp2 = (f16*)alloc((size_t)8 * 512 * 4 * 256 * 16 * 2);   // 128 MB
  f16* xt2 = (f16*)alloc((size_t)8 * 64 * 2 * 256 * 16 * 2);    // 8 MB
  f16* Bp  = (f16*)alloc((size_t)256 * 1024 * 2);
  f16* Bt  = (f16*)alloc((size_t)128 * 512 * 2);
  f16* U0f = (f16*)alloc((size_t)256 * 1024 * 2);
  f16* W1f = (f16*)alloc((size_t)256 * 512 * 2);
  f16* U1f = (f16*)alloc((size_t)128 * 512 * 2);
  f16* W2f = (f16*)alloc((size_t)128 * 256 * 2);
  f16* U2f = (f16*)alloc((size_t)64 * 256 * 2);
  f16* U0tf = (f16*)alloc((size_t)128 * 512 * 2);
  f16* W1tf = (f16*)alloc((size_t)128 * 256 * 2);
  f16* U1tf = (f16*)alloc((size_t)64 * 256 * 2);
  f16* h0r  = (f16*)alloc((size_t)8 * 8 * 4096 * 2);
  f16* h1r  = (f16*)alloc((size_t)8 * 8 * 2048 * 2);
  f16* h0tr = (f16*)alloc((size_t)8 * 8 * 2048 * 2);
  int* cnt  = (int*)alloc(96 * 4);
  float* feat = (float*)alloc((size_t)128 * 64 * 4);

  init_sync<<<32, 256, 0, stream>>>(cnt, h0r, h1r, h0tr);

  pack_bsw<8><<<1024, 256, 0, stream>>>(pl0_W, Bp, 1024);
  pack_bsw<4><<<256, 256, 0, stream>>>(tl0_W, Bt, 512);
  pack_bsw<8><<<1024, 256, 0, stream>>>(pl0_U, U0f, 1024);
  pack_bsw<8><<<512, 256, 0, stream>>>(pl1_W, W1f, 512);
  pack_bsw<4><<<256, 256, 0, stream>>>(pl1_U, U1f, 512);
  pack_bsw<4><<<128, 256, 0, stream>>>(pl2_W, W2f, 256);
  pack_bsw<2><<<64, 256, 0, stream>>>(pl2_U, U2f, 256);
  pack_bsw<4><<<256, 256, 0, stream>>>(tl0_U, U0tf, 512);
  pack_bsw<4><<<128, 256, 0, stream>>>(tl1_W, W1tf, 256);
  pack_bsw<2><<<64, 256, 0, stream>>>(tl1_U, U1tf, 256);
  gemm_xw<256, 8, 1024, 64, 0><<<1024, 256, 0, stream>>>(p_tok, emb_p, Bp, pl0_b, xp2);
  gemm_xw<128, 4, 512, 32, 1><<<128, 256, 0, stream>>>(t_tok, emb_t, Bt, tl0_b, xt2);

  RArgs ra;
  ra.xp2 = xp2; ra.xt2 = xt2;
  ra.U0f = U0f; ra.W1f = W1f; ra.U1f = U1f; ra.W2f = W2f; ra.U2f = U2f;
  ra.U0tf = U0tf; ra.W1tf = W1tf; ra.U1tf = U1tf;
  ra.pl1_b = pl1_b; ra.pl2_b = pl2_b; ra.tl1_b = tl1_b;
  ra.pd0W = pd0_W; ra.pd0b = pd0_b; ra.pd1W = pd1_W; ra.pd1b = pd1_b;
  ra.pd2W = pd2_W; ra.pd2b = pd2_b;
  ra.td0W = td0_W; ra.td0b = td0_b; ra.td1W = td1_W; ra.td1b = td1_b;
  ra.td2W = td2_W; ra.td2b = td2_b;
  ra.h0r = h0r; ra.h1r = h1r; ra.h0tr = h0tr;
  ra.cnt = cnt; ra.feat = feat;
  recur4<<<96, 256, 0, stream>>>(ra);

  head_kernel<<<1, 256, 0, stream>>>(feat, L0_W, L0_b, L1_W, L1_b, L2_W, L2_b,
                                     L3_W, L3_b, (float*)d_out);
}

// Round 5
// 3106.782 us; speedup vs baseline: 4.3299x; 4.3299x over previous
//
#include <hip/hip_runtime.h>
#include <hip/hip_fp16.h>

typedef _Float16 f16;
typedef _Float16 f16x8 __attribute__((ext_vector_type(8)));
typedef float    f32x4 __attribute__((ext_vector_type(4)));
typedef unsigned short ushort;
typedef unsigned int uint;

__device__ __forceinline__ float sigm(float x) { return 1.f / (1.f + __expf(-x)); }
__device__ __forceinline__ float reluf(float x) { return x > 0.f ? x : 0.f; }
__device__ __forceinline__ float h2f(ushort u) { return (float)__builtin_bit_cast(f16, u); }
__device__ __forceinline__ ushort f2h(float v) { return __builtin_bit_cast(ushort, (f16)v); }

#define LDRLX(p)    __hip_atomic_load((p), __ATOMIC_RELAXED, __HIP_MEMORY_SCOPE_AGENT)
#define STRLX(p, v) __hip_atomic_store((p), (v), __ATOMIC_RELAXED, __HIP_MEMORY_SCOPE_AGENT)
#define MFMA16(a, b, c) __builtin_amdgcn_mfma_f32_16x16x32_f16((a), (b), (c), 0, 0, 0)

// ---------------- pack B for MFMA b-frag layout (validated R1-R4)
template <int KF>
__global__ void pack_bsw(const float* __restrict__ B, f16* __restrict__ dst, int N) {
  int id = blockIdx.x * 256 + threadIdx.x;
  int total = KF * 32 * N;
  if (id >= total) return;
  int j  = id & 7;
  int L  = (id >> 3) & 63;
  int r  = id >> 9;
  int kf = r & (KF - 1);
  int c  = r / KF;
  int k  = kf * 32 + ((L >> 4) * 8) + j;
  int n  = c * 16 + (L & 15);
  dst[id] = (f16)B[k * N + n];
}

// ---------------- xW GEMM into recurrence x-layout (validated R4, absmax 0.0)
template <int K, int KF, int N, int NC, int MODE>
__global__ __launch_bounds__(256) void gemm_xw(const int* __restrict__ tok,
                                               const float* __restrict__ emb,
                                               const f16* __restrict__ Bsw,
                                               const float* __restrict__ bias,
                                               f16* __restrict__ X) {
  __shared__ int tokLds[64];
  __shared__ f16x8 bLds[8 * 64];
  const int tid = threadIdx.x;
  const int blk = blockIdx.x;
  if (tid < 64) tokLds[tid] = tok[blk * 64 + tid];
  __syncthreads();
  const int wave = tid >> 6, lane = tid & 63;
  const int quad = lane >> 4, l16 = lane & 15;
  const int m0 = wave * 16;

  f16x8 a[KF];
  {
    const int row = m0 + l16;
    const float* arow = emb + (long)tokLds[row] * K + quad * 8;
#pragma unroll
    for (int kf = 0; kf < KF; kf++) {
      float4 v0 = *(const float4*)(arow + kf * 32);
      float4 v1 = *(const float4*)(arow + kf * 32 + 4);
      f16x8 tv;
      tv[0] = (f16)v0.x; tv[1] = (f16)v0.y; tv[2] = (f16)v0.z; tv[3] = (f16)v0.w;
      tv[4] = (f16)v1.x; tv[5] = (f16)v1.y; tv[6] = (f16)v1.z; tv[7] = (f16)v1.w;
      a[kf] = tv;
    }
  }
  const f16x8* Bfrag = (const f16x8*)Bsw;
  for (int c = 0; c < NC; c++) {
    for (int i = tid; i < KF * 64; i += 256) bLds[i] = Bfrag[c * KF * 64 + i];
    __syncthreads();
    f32x4 acc = {0.f, 0.f, 0.f, 0.f};
#pragma unroll
    for (int kf = 0; kf < KF; kf++)
      acc = MFMA16(a[kf], bLds[kf * 64 + lane], acc);
    const int col = c * 16 + l16;
    const float bc = bias[col];
#pragma unroll
    for (int r = 0; r < 4; r++) {
      float v = acc[r] + bc;
      int row = blk * 64 + m0 + quad * 4 + r;
      size_t addr;
      if (MODE == 0) {
        int seqg = row >> 9, t = row & 511;
        int gg = seqg >> 4, si = seqg & 15, qc = si >> 2, rr = si & 3;
        int gm = col >> 8, u = col & 255, bb = u >> 6, wv = (u >> 4) & 3, l = u & 15;
        addr = (((size_t)((gg * 512 + t) * 4 + bb) * 256 + (wv * 64 + qc * 16 + l)) * 16 + rr * 4 + gm);
      } else {
        int seqg = row >> 6, t = row & 63;
        int gg = seqg >> 4, si = seqg & 15, qc = si >> 2, rr = si & 3;
        int gm = col >> 7, u = col & 127, bb = u >> 6, wv = (u >> 4) & 3, l = u & 15;
        addr = (((size_t)((gg * 64 + t) * 2 + bb) * 256 + (wv * 64 + qc * 16 + l)) * 16 + rr * 4 + gm);
      }
      X[addr] = (f16)v;
    }
    __syncthreads();
  }
}

// ---------------- init: zero the whole tag ring (required each replay)
__global__ void init_ring(uint* __restrict__ ring) {
  int i = blockIdx.x * 256 + threadIdx.x;
  if (i < 8 * 8 * 4096) ring[i] = 0u;
}

// ---------------- P0: paragraph L0, 32 blocks (g=blk>>2, bb=blk&3), tag-word ring
struct P0Args {
  const f16* xp2;
  const f16* U0f;
  uint* h0ring;     // [g][slot8][u*16+s]
  f16* h0seq;       // [((g*512+t)*16+s)*256+u]
};

__global__ __launch_bounds__(256, 1) void recur_p0(P0Args A) {
  __shared__ f16 wlds[8 * 512 * 8];   // 64 KB: g,o-gate b-frags (8 tiles)
  __shared__ f16 h0cur[16 * 264];
  const int tid = threadIdx.x;
  const int w = tid >> 6, lane = tid & 63;
  const int quad = lane >> 4, l16 = lane & 15;
  const int g = blockIdx.x >> 2, bb = blockIdx.x & 3;

  // load g,o weights into LDS
  const uint4* U0q = (const uint4*)A.U0f;
  uint4* wq = (uint4*)wlds;
  for (int idx = tid; idx < 4096; idx += 256) {
    int tau = idx >> 9, rem = idx & 511, kf = rem >> 6, ln = rem & 63;
    int gm = 2 + (tau >> 2), wv = tau & 3;
    int ct = gm * 16 + bb * 4 + wv;
    wq[idx] = U0q[(ct * 8 + kf) * 64 + ln];
  }
  // i,f weights in registers
  const f16x8* U0v = (const f16x8*)A.U0f;
  f16x8 wreg[2][8];
#pragma unroll
  for (int gm = 0; gm < 2; gm++)
#pragma unroll
    for (int kf = 0; kf < 8; kf++)
      wreg[gm][kf] = U0v[((gm * 16 + bb * 4 + w) * 8 + kf) * 64 + lane];
  for (int idx = tid; idx < 16 * 264; idx += 256) h0cur[idx] = (f16)0.f;
  float c0[4] = {0.f, 0.f, 0.f, 0.f};

  uint* ring = A.h0ring + (size_t)g * 8 * 4096;
  int pp[3];
  {
    int q = 0;
    for (int p = 0; p < 4; p++)
      if (p != bb) pp[q++] = p;
  }
  const int uL = tid >> 2, sB = 4 * (tid & 3);
  const uint4* xP = (const uint4*)A.xp2;
  const size_t xb0 = ((size_t)(g * 512 * 4 + bb) * 256 + tid) * 2;
  const f16x8* wldsv = (const f16x8*)wlds;
  __syncthreads();

  for (int t = 0; t < 512; t++) {
    // x for this step (issue before polls so it's hidden)
    uint4 xc0 = xP[xb0 + (size_t)t * 2048];
    uint4 xc1 = xP[xb0 + (size_t)t * 2048 + 1];
    // poll peers' h(t-1): tag = t (zeroed slot 7 serves t=0)
    const uint tag = (uint)t;
    uint* rs = ring + ((t + 7) & 7) * 4096;
    uint pv[12];
#pragma unroll
    for (int q = 0; q < 3; q++)
#pragma unroll
      for (int j = 0; j < 4; j++)
        pv[q * 4 + j] = LDRLX(rs + (64 * pp[q] + uL) * 16 + sB + j);
    for (;;) {
      bool ok = true;
#pragma unroll
      for (int k = 0; k < 12; k++)
        if ((pv[k] >> 16) != tag) {
          int q = k >> 2, j = k & 3;
          pv[k] = LDRLX(rs + (64 * pp[q] + uL) * 16 + sB + j);
          ok = false;
        }
      if (ok) break;
      __builtin_amdgcn_s_sleep(1);
    }
#pragma unroll
    for (int q = 0; q < 3; q++)
#pragma unroll
      for (int j = 0; j < 4; j++)
        h0cur[(sB + j) * 264 + 64 * pp[q] + uL] =
            __builtin_bit_cast(f16, (ushort)(pv[q * 4 + j] & 0xffffu));
    __syncthreads();
    f16x8 af[8];
#pragma unroll
    for (int kf = 0; kf < 8; kf++)
      af[kf] = *(const f16x8*)&h0cur[l16 * 264 + kf * 32 + quad * 8];
    __syncthreads();
    f32x4 z[4];
#pragma unroll
    for (int gm = 0; gm < 2; gm++) {
      f32x4 zz = {0.f, 0.f, 0.f, 0.f};
#pragma unroll
      for (int kf = 0; kf < 8; kf++) zz = MFMA16(af[kf], wreg[gm][kf], zz);
      z[gm] = zz;
    }
#pragma unroll
    for (int gm = 2; gm < 4; gm++) {
      f32x4 zz = {0.f, 0.f, 0.f, 0.f};
#pragma unroll
      for (int kf = 0; kf < 8; kf++)
        zz = MFMA16(af[kf], wldsv[((gm - 2) * 4 + w) * 512 + kf * 64 + lane], zz);
      z[gm] = zz;
    }
    ushort xs[16];
    *(uint4*)&xs[0] = xc0; *(uint4*)&xs[8] = xc1;
    const int u = 64 * bb + 16 * w + l16;
#pragma unroll
    for (int r = 0; r < 4; r++) {
      float gi = sigm(z[0][r] + h2f(xs[r * 4 + 0]));
      float ff = sigm(z[1][r] + h2f(xs[r * 4 + 1]));
      float gg = reluf(z[2][r] + h2f(xs[r * 4 + 2]));
      float oo = sigm(z[3][r] + h2f(xs[r * 4 + 3]));
      c0[r] = ff * c0[r] + gi * gg;
      float h = oo * reluf(c0[r]);
      ushort hb = f2h(h);
      const int s = quad * 4 + r;
      h0cur[s * 264 + u] = __builtin_bit_cast(f16, hb);
      STRLX(ring + (t & 7) * 4096 + u * 16 + s, ((uint)(t + 1) << 16) | (uint)hb);
      A.h0seq[((size_t)(g * 512 + t) * 16 + s) * 256 + u] = __builtin_bit_cast(f16, hb);
    }
  }
}

// ---------------- P1: paragraph L1, 8 blocks x 512 thr, reads h0seq, writes h1seq
struct P1Args {
  const f16* h0seq;
  const f16 *W1f, *U1f;
  const float* pl1_b;
  f16* h1seq;      // [((g*512+t)*16+s)*128+u]
};

__global__ __launch_bounds__(512, 1) void recur_p1(P1Args A) {
  __shared__ f16 U1lds[65536];        // 128 KB
  __shared__ f16 h0cur[16 * 264];
  __shared__ f16 h1db[2][16 * 136];
  const int tid = threadIdx.x;
  const int w = tid >> 6, lane = tid & 63;
  const int quad = lane >> 4, l16 = lane & 15;
  const int g = blockIdx.x;

  {
    const uint4* src = (const uint4*)A.U1f;
    uint4* dst = (uint4*)U1lds;
    for (int idx = tid; idx < 8192; idx += 512) dst[idx] = src[idx];
  }
  const f16x8* W1v = (const f16x8*)A.W1f;
  f16x8 wreg[4][8];
  float b1[4];
#pragma unroll
  for (int gm = 0; gm < 4; gm++) {
#pragma unroll
    for (int kf = 0; kf < 8; kf++)
      wreg[gm][kf] = W1v[((w + 8 * gm) * 8 + kf) * 64 + lane];
    b1[gm] = A.pl1_b[gm * 128 + 16 * w + l16];
  }
  for (int idx = tid; idx < 16 * 136; idx += 512) h1db[0][idx] = (f16)0.f;
  float c1[4] = {0.f, 0.f, 0.f, 0.f};

  const uint4* hsrc = (const uint4*)A.h0seq + (size_t)g * 512 * 512;
  const f16x8* U1v = (const f16x8*)U1lds;
  uint4 cur = hsrc[tid];
  __syncthreads();

  for (int t = 0; t < 512; t++) {
    uint4 nxt = hsrc[(size_t)(t + 1 < 512 ? t + 1 : t) * 512 + tid];
    *(uint4*)&h0cur[(tid >> 5) * 264 + (tid & 31) * 8] = cur;
    __syncthreads();
    f16x8 af0[8], af1[4];
#pragma unroll
    for (int kf = 0; kf < 8; kf++)
      af0[kf] = *(const f16x8*)&h0cur[l16 * 264 + kf * 32 + quad * 8];
#pragma unroll
    for (int kf = 0; kf < 4; kf++)
      af1[kf] = *(const f16x8*)&h1db[t & 1][l16 * 136 + kf * 32 + quad * 8];
    __syncthreads();
    f32x4 z[4];
#pragma unroll
    for (int gm = 0; gm < 4; gm++) {
      f32x4 zz = {0.f, 0.f, 0.f, 0.f};
#pragma unroll
      for (int kf = 0; kf < 8; kf++) zz = MFMA16(af0[kf], wreg[gm][kf], zz);
#pragma unroll
      for (int kf = 0; kf < 4; kf++)
        zz = MFMA16(af1[kf], U1v[((w + 8 * gm) * 4 + kf) * 64 + lane], zz);
      z[gm] = zz;
    }
    const int u = 16 * w + l16;
#pragma unroll
    for (int r = 0; r < 4; r++) {
      float gi = sigm(z[0][r] + b1[0]);
      float ff = sigm(z[1][r] + b1[1]);
      float gg = reluf(z[2][r] + b1[2]);
      float oo = sigm(z[3][r] + b1[3]);
      c1[r] = ff * c1[r] + gi * gg;
      f16 h = (f16)(oo * reluf(c1[r]));
      const int s = quad * 4 + r;
      h1db[(t + 1) & 1][s * 136 + u] = h;
      A.h1seq[((size_t)(g * 512 + t) * 16 + s) * 128 + u] = h;
    }
    cur = nxt;
  }
}

// ---------------- P2 + Title: 16 blocks x 256 thr
struct P2TArgs {
  const f16* h1seq;
  const f16 *W2f, *U2f;
  const float* pl2_b;
  const float *pd0W, *pd0b, *pd1W, *pd1b, *pd2W, *pd2b;
  const f16* xt2;
  const f16 *U0tf, *W1tf, *U1tf;
  const float* tl1_b;
  const float *td0W, *td0b, *td1W, *td1b, *td2W, *td2b;
  float* feat;
};

__global__ __launch_bounds__(256, 1) void recur_p2t(P2TArgs A) {
  __shared__ __align__(16) char smem[157184];
  const int tid = threadIdx.x;
  const int w = tid >> 6, lane = tid & 63;
  const int quad = lane >> 4, l16 = lane & 15;
  const int blk = blockIdx.x;
  float* zmA = (float*)(smem + 144384);   // 16 x 132 f32
  float* zmB = (float*)(smem + 152832);   // 16 x 68  f32

  if (blk < 8) {
    // ========== paragraph L2 + dense tail ==========
    const int g = blk;
    f16* h1cur = (f16*)(smem + 131072);       // 16 x 136
    f16* h2db  = (f16*)(smem + 139776);       // 2 x 16 x 72
    const f16x8* W2v = (const f16x8*)A.W2f;
    const f16x8* U2v = (const f16x8*)A.U2f;
    f16x8 wB[4][4], wU[4][2];
    float b2[4];
#pragma unroll
    for (int gm = 0; gm < 4; gm++) {
#pragma unroll
      for (int kf = 0; kf < 4; kf++) wB[gm][kf] = W2v[((w + 4 * gm) * 4 + kf) * 64 + lane];
#pragma unroll
      for (int kf = 0; kf < 2; kf++) wU[gm][kf] = U2v[((w + 4 * gm) * 2 + kf) * 64 + lane];
      b2[gm] = A.pl2_b[gm * 64 + 16 * w + l16];
    }
    for (int idx = tid; idx < 16 * 72; idx += 256) h2db[idx] = (f16)0.f;
    float c2[4] = {0.f, 0.f, 0.f, 0.f};
    const uint4* hsrc = (const uint4*)A.h1seq + (size_t)g * 512 * 256;
    uint4 cur = hsrc[tid];
    __syncthreads();

    for (int t = 0; t < 512; t++) {
      uint4 nxt = hsrc[(size_t)(t + 1 < 512 ? t + 1 : t) * 256 + tid];
      *(uint4*)&h1cur[(tid >> 4) * 136 + (tid & 15) * 8] = cur;
      __syncthreads();
      f16x8 af0[4], af1[2];
#pragma unroll
      for (int kf = 0; kf < 4; kf++)
        af0[kf] = *(const f16x8*)&h1cur[l16 * 136 + kf * 32 + quad * 8];
#pragma unroll
      for (int kf = 0; kf < 2; kf++)
        af1[kf] = *(const f16x8*)&h2db[(t & 1) * 16 * 72 + l16 * 72 + kf * 32 + quad * 8];
      __syncthreads();
      f32x4 z[4];
#pragma unroll
      for (int gm = 0; gm < 4; gm++) {
        f32x4 zz = {0.f, 0.f, 0.f, 0.f};
#pragma unroll
        for (int kf = 0; kf < 4; kf++) zz = MFMA16(af0[kf], wB[gm][kf], zz);
#pragma unroll
        for (int kf = 0; kf < 2; kf++) zz = MFMA16(af1[kf], wU[gm][kf], zz);
        z[gm] = zz;
      }
      const int u = 16 * w + l16;
#pragma unroll
      for (int r = 0; r < 4; r++) {
        float gi = sigm(z[0][r] + b2[0]);
        float ff = sigm(z[1][r] + b2[1]);
        float gg = reluf(z[2][r] + b2[2]);
        float oo = sigm(z[3][r] + b2[3]);
        c2[r] = ff * c2[r] + gi * gg;
        h2db[((t + 1) & 1) * 16 * 72 + (quad * 4 + r) * 72 + u] = (f16)(oo * reluf(c2[r]));
      }
      cur = nxt;
    }
    __syncthreads();
    const f16* hf = h2db;  // parity 0 after 512 steps
#pragma unroll 1
    for (int e = 0; e < 8; e++) {
      const int idx = tid + 256 * e, sq = idx >> 7, j = idx & 127;
      float a = A.pd0b[j];
      for (int k = 0; k < 64; k++) a += (float)hf[sq * 72 + k] * A.pd0W[k * 128 + j];
      zmA[sq * 132 + j] = reluf(a);
    }
    __syncthreads();
#pragma unroll 1
    for (int e = 0; e < 4; e++) {
      const int idx = tid + 256 * e, sq = idx >> 6, j = idx & 63;
      float a = A.pd1b[j];
      for (int k = 0; k < 128; k++) a += zmA[sq * 132 + k] * A.pd1W[k * 64 + j];
      zmB[sq * 68 + j] = reluf(a);
    }
    __syncthreads();
#pragma unroll 1
    for (int e = 0; e < 2; e++) {
      const int idx = tid + 256 * e, sq = idx >> 5, j = idx & 31;
      float a = A.pd2b[j];
      for (int k = 0; k < 64; k++) a += zmB[sq * 68 + k] * A.pd2W[k * 32 + j];
      A.feat[(g * 16 + sq) * 64 + 32 + j] = a;
    }
  } else {
    // ========== title full stack (self-contained) ==========
    const int g = blk - 8;
    f16* wldsT = (f16*)smem;                  // 128 KB U0t b-frags
    f16* h0db  = (f16*)(smem + 131072);       // 2 x 16 x 136
    f16* h1db  = (f16*)(smem + 139776);       // 2 x 16 x 72
    {
      const uint4* src = (const uint4*)A.U0tf;
      uint4* dst = (uint4*)wldsT;
      for (int idx = tid; idx < 8192; idx += 256) dst[idx] = src[idx];
    }
    const f16x8* W1tv = (const f16x8*)A.W1tf;
    const f16x8* U1tv = (const f16x8*)A.U1tf;
    f16x8 wB[4][4], wU[4][2];
    float bt[4];
#pragma unroll
    for (int gm = 0; gm < 4; gm++) {
#pragma unroll
      for (int kf = 0; kf < 4; kf++) wB[gm][kf] = W1tv[((w + 4 * gm) * 4 + kf) * 64 + lane];
#pragma unroll
      for (int kf = 0; kf < 2; kf++) wU[gm][kf] = U1tv[((w + 4 * gm) * 2 + kf) * 64 + lane];
      bt[gm] = A.tl1_b[gm * 64 + 16 * w + l16];
    }
    for (int idx = tid; idx < 16 * 136; idx += 256) h0db[idx] = (f16)0.f;
    for (int idx = tid; idx < 16 * 72; idx += 256) h1db[idx] = (f16)0.f;
    float c0t[2][4] = {}, c1t[4] = {};
    const uint4* xP = (const uint4*)A.xt2;
    // per-lane x addressing for the 2 unit-tiles (ut = 2w+j2)
    size_t xbase[2];
#pragma unroll
    for (int j2 = 0; j2 < 2; j2++) {
      int u = 32 * w + 16 * j2 + l16;
      int bbx = u >> 6, wvx = (u >> 4) & 3;
      xbase[j2] = ((size_t)((g * 64 + 0) * 2 + bbx) * 256 + wvx * 64 + quad * 16 + l16) * 2;
    }
    const f16x8* wldv = (const f16x8*)wldsT;
    __syncthreads();

    for (int t = 0; t < 64; t++) {
      // ---- L0t
      f16x8 af[4];
#pragma unroll
      for (int kf = 0; kf < 4; kf++)
        af[kf] = *(const f16x8*)&h0db[(t & 1) * 16 * 136 + l16 * 136 + kf * 32 + quad * 8];
      ushort xs[2][16];
#pragma unroll
      for (int j2 = 0; j2 < 2; j2++) {
        size_t xi = xbase[j2] + (size_t)t * 1024;
        *(uint4*)&xs[j2][0] = xP[xi];
        *(uint4*)&xs[j2][8] = xP[xi + 1];
      }
#pragma unroll
      for (int j2 = 0; j2 < 2; j2++) {
        const int ut = 2 * w + j2;
        f32x4 z[4];
#pragma unroll
        for (int gm = 0; gm < 4; gm++) {
          f32x4 zz = {0.f, 0.f, 0.f, 0.f};
#pragma unroll
          for (int kf = 0; kf < 4; kf++)
            zz = MFMA16(af[kf], wldv[((ut + 8 * gm) * 4 + kf) * 64 + lane], zz);
          z[gm] = zz;
        }
#pragma unroll
        for (int r = 0; r < 4; r++) {
          float gi = sigm(z[0][r] + h2f(xs[j2][r * 4 + 0]));
          float ff = sigm(z[1][r] + h2f(xs[j2][r * 4 + 1]));
          float gg = reluf(z[2][r] + h2f(xs[j2][r * 4 + 2]));
          float oo = sigm(z[3][r] + h2f(xs[j2][r * 4 + 3]));
          c0t[j2][r] = ff * c0t[j2][r] + gi * gg;
          h0db[((t + 1) & 1) * 16 * 136 + (quad * 4 + r) * 136 + 16 * ut + l16] =
              (f16)(oo * reluf(c0t[j2][r]));
        }
      }
      __syncthreads();
      // ---- L1t
      f16x8 afC[4], afU[2];
#pragma unroll
      for (int kf = 0; kf < 4; kf++)
        afC[kf] = *(const f16x8*)&h0db[((t + 1) & 1) * 16 * 136 + l16 * 136 + kf * 32 + quad * 8];
#pragma unroll
      for (int kf = 0; kf < 2; kf++)
        afU[kf] = *(const f16x8*)&h1db[(t & 1) * 16 * 72 + l16 * 72 + kf * 32 + quad * 8];
      f32x4 z[4];
#pragma unroll
      for (int gm = 0; gm < 4; gm++) {
        f32x4 zz = {0.f, 0.f, 0.f, 0.f};
#pragma unroll
        for (int kf = 0; kf < 4; kf++) zz = MFMA16(afC[kf], wB[gm][kf], zz);
#pragma unroll
        for (int kf = 0; kf < 2; kf++) zz = MFMA16(afU[kf], wU[gm][kf], zz);
        z[gm] = zz;
      }
#pragma unroll
      for (int r = 0; r < 4; r++) {
        float gi = sigm(z[0][r] + bt[0]);
        float ff = sigm(z[1][r] + bt[1]);
        float gg = reluf(z[2][r] + bt[2]);
        float oo = sigm(z[3][r] + bt[3]);
        c1t[r] = ff * c1t[r] + gi * gg;
        h1db[((t + 1) & 1) * 16 * 72 + (quad * 4 + r) * 72 + 16 * w + l16] =
            (f16)(oo * reluf(c1t[r]));
      }
      __syncthreads();
    }
    const f16* hf = h1db;  // parity 0 after 64 steps
#pragma unroll 1
    for (int e = 0; e < 8; e++) {
      const int idx = tid + 256 * e, sq = idx >> 7, j = idx & 127;
      float a = A.td0b[j];
      for (int k = 0; k < 64; k++) a += (float)hf[sq * 72 + k] * A.td0W[k * 128 + j];
      zmA[sq * 132 + j] = reluf(a);
    }
    __syncthreads();
#pragma unroll 1
    for (int e = 0; e < 4; e++) {
      const int idx = tid + 256 * e, sq = idx >> 6, j = idx & 63;
      float a = A.td1b[j];
      for (int k = 0; k < 128; k++) a += zmA[sq * 132 + k] * A.td1W[k * 64 + j];
      zmB[sq * 68 + j] = reluf(a);
    }
    __syncthreads();
#pragma unroll 1
    for (int e = 0; e < 2; e++) {
      const int idx = tid + 256 * e, sq = idx >> 5, j = idx & 31;
      float a = A.td2b[j];
      for (int k = 0; k < 64; k++) a += zmB[sq * 68 + k] * A.td2W[k * 32 + j];
      A.feat[(g * 16 + sq) * 64 + j] = a;
    }
  }
}

// ---------------- head: mean over 16, 4 dense layers, sigmoid
__global__ __launch_bounds__(256) void head_kernel(const float* __restrict__ feat,
    const float* __restrict__ L0W, const float* __restrict__ L0b,
    const float* __restrict__ L1W, const float* __restrict__ L1b,
    const float* __restrict__ L2W, const float* __restrict__ L2b,
    const float* __restrict__ L3W, const float* __restrict__ L3b,
    float* __restrict__ out) {
  __shared__ float xb[512];
  __shared__ float y0[2048];
  __shared__ float y1[1024];
  __shared__ float y2[512];
  const int tid = threadIdx.x;
  for (int idx = tid; idx < 512; idx += 256) {
    int b = idx >> 6, d = idx & 63;
    float s = 0.f;
    for (int n = 0; n < 16; n++) s += feat[(b * 16 + n) * 64 + d];
    xb[idx] = s * (1.f / 16.f);
  }
  __syncthreads();
  for (int idx = tid; idx < 2048; idx += 256) {
    int b = idx >> 8, j = idx & 255;
    float a = L0b[j];
    for (int k = 0; k < 64; k++) a += xb[b * 64 + k] * L0W[k * 256 + j];
    y0[idx] = reluf(a);
  }
  __syncthreads();
  for (int idx = tid; idx < 1024; idx += 256) {
    int b = idx >> 7, j = idx & 127;
    float a = L1b[j];
    for (int k = 0; k < 256; k++) a += y0[b * 256 + k] * L1W[k * 128 + j];
    y1[idx] = reluf(a);
  }
  __syncthreads();
  for (int idx = tid; idx < 512; idx += 256) {
    int b = idx >> 6, j = idx & 63;
    float a = L2b[j];
    for (int k = 0; k < 128; k++) a += y1[b * 128 + k] * L2W[k * 64 + j];
    y2[idx] = reluf(a);
  }
  __syncthreads();
  {
    int b = tid >> 5, j = tid & 31;
    float a = L3b[j];
    for (int k = 0; k < 64; k++) a += y2[b * 64 + k] * L3W[k * 32 + j];
    out[b * 32 + j] = 1.f / (1.f + __expf(-a));
  }
}

extern "C" void kernel_launch(void* const* d_in, const int* in_sizes, int n_in,
                              void* d_out, int out_size, void* d_ws, size_t ws_size,
                              hipStream_t stream) {
  const int*   t_tok = (const int*)d_in[0];
  const int*   p_tok = (const int*)d_in[1];
  const float* emb_t = (const float*)d_in[2];
  const float* emb_p = (const float*)d_in[3];
  const float* tl0_W = (const float*)d_in[4];
  const float* tl0_U = (const float*)d_in[5];
  const float* tl0_b = (const float*)d_in[6];
  const float* tl1_W = (const float*)d_in[7];
  const float* tl1_U = (const float*)d_in[8];
  const float* tl1_b = (const float*)d_in[9];
  const float* td0_W = (const float*)d_in[10];
  const float* td0_b = (const float*)d_in[11];
  const float* td1_W = (const float*)d_in[12];
  const float* td1_b = (const float*)d_in[13];
  const float* td2_W = (const float*)d_in[14];
  const float* td2_b = (const float*)d_in[15];
  const float* pl0_W = (const float*)d_in[16];
  const float* pl0_U = (const float*)d_in[17];
  const float* pl0_b = (const float*)d_in[18];
  const float* pl1_W = (const float*)d_in[19];
  const float* pl1_U = (const float*)d_in[20];
  const float* pl1_b = (const float*)d_in[21];
  const float* pl2_W = (const float*)d_in[22];
  const float* pl2_U = (const float*)d_in[23];
  const float* pl2_b = (const float*)d_in[24];
  const float* pd0_W = (const float*)d_in[25];
  const float* pd0_b = (const float*)d_in[26];
  const float* pd1_W = (const float*)d_in[27];
  const float* pd1_b = (const float*)d_in[28];
  const float* pd2_W = (const float*)d_in[29];
  const float* pd2_b = (const float*)d_in[30];
  const float* L0_W  = (const float*)d_in[31];
  const float* L0_b  = (const float*)d_in[32];
  const float* L1_W  = (const float*)d_in[33];
  const float* L1_b  = (const float*)d_in[34];
  const float* L2_W  = (const float*)d_in[35];
  const float* L2_b  = (const float*)d_in[36];
  const float* L3_W  = (const float*)d_in[37];
  const float* L3_b  = (const float*)d_in[38];

  char* ws = (char*)d_ws;
  size_t off = 0;
  auto alloc = [&](size_t bytes) {
    void* ptr = ws + off;
    off += (bytes + 255) & ~(size_t)255;
    return ptr;
  };
  f16* xp2  = (f16*)alloc((size_t)8 * 512 * 4 * 256 * 16 * 2);   // 128 MB
  f16* xt2  = (f16*)alloc((size_t)8 * 64 * 2 * 256 * 16 * 2);    // 8 MB
  f16* Bp   = (f16*)alloc((size_t)256 * 1024 * 2);
  f16* Bt   = (f16*)alloc((size_t)128 * 512 * 2);
  f16* U0f  = (f16*)alloc((size_t)256 * 1024 * 2);
  f16* W1f  = (f16*)alloc((size_t)256 * 512 * 2);
  f16* U1f  = (f16*)alloc((size_t)128 * 512 * 2);
  f16* W2f  = (f16*)alloc((size_t)128 * 256 * 2);
  f16* U2f  = (f16*)alloc((size_t)64 * 256 * 2);
  f16* U0tf = (f16*)alloc((size_t)128 * 512 * 2);
  f16* W1tf = (f16*)alloc((size_t)128 * 256 * 2);
  f16* U1tf = (f16*)alloc((size_t)64 * 256 * 2);
  uint* h0ring = (uint*)alloc((size_t)8 * 8 * 4096 * 4);         // 1 MB
  f16* h0seq = (f16*)alloc((size_t)8 * 512 * 16 * 256 * 2);      // 32 MB
  f16* h1seq = (f16*)alloc((size_t)8 * 512 * 16 * 128 * 2);      // 16 MB
  float* feat = (float*)alloc((size_t)128 * 64 * 4);

  init_ring<<<1024, 256, 0, stream>>>(h0ring);

  pack_bsw<8><<<1024, 256, 0, stream>>>(pl0_W, Bp, 1024);
  pack_bsw<4><<<256, 256, 0, stream>>>(tl0_W, Bt, 512);
  pack_bsw<8><<<1024, 256, 0, stream>>>(pl0_U, U0f, 1024);
  pack_bsw<8><<<512, 256, 0, stream>>>(pl1_W, W1f, 512);
  pack_bsw<4><<<256, 256, 0, stream>>>(pl1_U, U1f, 512);
  pack_bsw<4><<<128, 256, 0, stream>>>(pl2_W, W2f, 256);
  pack_bsw<2><<<64, 256, 0, stream>>>(pl2_U, U2f, 256);
  pack_bsw<4><<<256, 256, 0, stream>>>(tl0_U, U0tf, 512);
  pack_bsw<4><<<128, 256, 0, stream>>>(tl1_W, W1tf, 256);
  pack_bsw<2><<<64, 256, 0, stream>>>(tl1_U, U1tf, 256);
  gemm_xw<256, 8, 1024, 64, 0><<<1024, 256, 0, stream>>>(p_tok, emb_p, Bp, pl0_b, xp2);
  gemm_xw<128, 4, 512, 32, 1><<<128, 256, 0, stream>>>(t_tok, emb_t, Bt, tl0_b, xt2);

  P0Args a0;
  a0.xp2 = xp2; a0.U0f = U0f; a0.h0ring = h0ring; a0.h0seq = h0seq;
  recur_p0<<<32, 256, 0, stream>>>(a0);

  P1Args a1;
  a1.h0seq = h0seq; a1.W1f = W1f; a1.U1f = U1f; a1.pl1_b = pl1_b; a1.h1seq = h1seq;
  recur_p1<<<8, 512, 0, stream>>>(a1);

  P2TArgs a2;
  a2.h1seq = h1seq; a2.W2f = W2f; a2.U2f = U2f; a2.pl2_b = pl2_b;
  a2.pd0W = pd0_W; a2.pd0b = pd0_b; a2.pd1W = pd1_W; a2.pd1b = pd1_b;
  a2.pd2W = pd2_W; a2.pd2b = pd2_b;
  a2.xt2 = xt2; a2.U0tf = U0tf; a2.W1tf = W1tf; a2.U1tf = U1tf; a2.tl1_b = tl1_b;
  a2.td0W = td0_W; a2.td0b = td0_b; a2.td1W = td1_W; a2.td1b = td1_b;
  a2.td2W = td2_W; a2.td2b = td2_b;
  a2.feat = feat;
  recur_p2t<<<16, 256, 0, stream>>>(a2);

  head_kernel<<<1, 256, 0, stream>>>(feat, L0_W, L0_b, L1_W, L1_b, L2_W, L2_b,
                                     L3_W, L3_b, (float*)d_out);
}